// Round 4
// baseline (203.701 us; speedup 1.0000x reference)
//
#include <hip/hip_runtime.h>
#include <hip/hip_bf16.h>

// DotAttention: B=64, S=4096, H=1024, f32 inputs, **f32 outputs**.
// out layout (flat f32): [B, 2H] concat(context, dec)  then  [B, S] weights.
//
// Split-S single-pass-over-enc with online softmax:
//   pass_a  : per (b, chunk) -> partial (ctx[H], m, l) + raw scores  (1024 blocks)
//   finalize: merge 16 partials per batch, emit all f32 outputs      (64 blocks)

#define NB 64
#define NS 4096
#define NH 1024
#define CHUNKS 16
#define ROWS (NS / CHUNKS)            // 256 rows per block
#define NTHREADS 256
#define NWAVES 4
#define ROWS_PER_WAVE (ROWS / NWAVES) // 64
#define PSTRIDE (NH + 2)              // ctx[NH], m, l

__global__ __launch_bounds__(NTHREADS)
void dotattn_pass_a(const float* __restrict__ enc, const float* __restrict__ dec,
                    float* __restrict__ scores, float* __restrict__ partials)
{
    const int blk   = blockIdx.x;
    const int b     = blk >> 4;    // / CHUNKS
    const int chunk = blk & 15;    // % CHUNKS
    const int tid   = threadIdx.x;
    const int lane  = tid & 63;
    const int wave  = tid >> 6;

    // Lane owns h-slice {lane*4 + k*256 + j : k,j in 0..3} (16 of 1024).
    const float* decb = dec + b * NH;
    float4 dreg[4];
#pragma unroll
    for (int k = 0; k < 4; ++k)
        dreg[k] = *reinterpret_cast<const float4*>(decb + lane * 4 + k * 256);

    float4 ctx[4];
#pragma unroll
    for (int k = 0; k < 4; ++k) ctx[k] = make_float4(0.f, 0.f, 0.f, 0.f);
    float m = -3.0e38f, l = 0.f;

    const int s0 = chunk * ROWS;
    const float* encb = enc + (size_t)b * NS * NH;

    // prefetch row i=0 for this wave
    float4 en[4];
    {
        const size_t base = (size_t)(s0 + wave) * NH + lane * 4;
#pragma unroll
        for (int k = 0; k < 4; ++k)
            en[k] = *reinterpret_cast<const float4*>(encb + base + k * 256);
    }

    for (int i = 0; i < ROWS_PER_WAVE; ++i) {
        const int s = s0 + wave + NWAVES * i;      // wave-interleaved rows
        float4 e[4];
#pragma unroll
        for (int k = 0; k < 4; ++k) e[k] = en[k];

        if (i + 1 < ROWS_PER_WAVE) {
            const size_t nbase = (size_t)(s + NWAVES) * NH + lane * 4;
#pragma unroll
            for (int k = 0; k < 4; ++k)
                en[k] = *reinterpret_cast<const float4*>(encb + nbase + k * 256);
        }

        float p = 0.f;
#pragma unroll
        for (int k = 0; k < 4; ++k) {
            p += e[k].x * dreg[k].x;
            p += e[k].y * dreg[k].y;
            p += e[k].z * dreg[k].z;
            p += e[k].w * dreg[k].w;
        }
#pragma unroll
        for (int off = 32; off >= 1; off >>= 1)
            p += __shfl_xor(p, off, 64);            // row score on every lane

        if (lane == 0) scores[b * NS + s] = p;

        if (p > m) {                                // wave-uniform branch
            const float sc = __expf(m - p);
            l *= sc;
#pragma unroll
            for (int k = 0; k < 4; ++k) {
                ctx[k].x *= sc; ctx[k].y *= sc; ctx[k].z *= sc; ctx[k].w *= sc;
            }
            m = p;
        }
        const float w = __expf(p - m);
        l += w;
#pragma unroll
        for (int k = 0; k < 4; ++k) {               // reuse enc row in-register
            ctx[k].x += w * e[k].x; ctx[k].y += w * e[k].y;
            ctx[k].z += w * e[k].z; ctx[k].w += w * e[k].w;
        }
    }

    // ---- combine 4 waves -> one partial per block ----
    __shared__ float sml[NWAVES][2];
    __shared__ float sctx[NWAVES][NH];             // 16 KiB

    if (lane == 0) { sml[wave][0] = m; sml[wave][1] = l; }
    __syncthreads();

    const float M = fmaxf(fmaxf(sml[0][0], sml[1][0]), fmaxf(sml[2][0], sml[3][0]));
    float L = 0.f;
#pragma unroll
    for (int wv = 0; wv < NWAVES; ++wv)
        L += sml[wv][1] * __expf(sml[wv][0] - M);

    const float msc = __expf(m - M);               // wave-uniform
#pragma unroll
    for (int k = 0; k < 4; ++k) {
        float4 v = make_float4(ctx[k].x * msc, ctx[k].y * msc,
                               ctx[k].z * msc, ctx[k].w * msc);
        *reinterpret_cast<float4*>(&sctx[wave][lane * 4 + k * 256]) = v;
    }
    __syncthreads();

    float* outp = partials + (size_t)(b * CHUNKS + chunk) * PSTRIDE;
    for (int h = tid; h < NH; h += NTHREADS)
        outp[h] = sctx[0][h] + sctx[1][h] + sctx[2][h] + sctx[3][h];
    if (tid == 0) { outp[NH] = M; outp[NH + 1] = L; }
}

__global__ __launch_bounds__(NTHREADS)
void dotattn_finalize(const float* __restrict__ dec, const float* __restrict__ scores,
                      const float* __restrict__ partials, float* __restrict__ out)
{
    const int b   = blockIdx.x;
    const int tid = threadIdx.x;
    const float* pb = partials + (size_t)b * CHUNKS * PSTRIDE;

    float M = -3.0e38f;
#pragma unroll
    for (int c = 0; c < CHUNKS; ++c)
        M = fmaxf(M, pb[c * PSTRIDE + NH]);

    float scale[CHUNKS];
    float L = 0.f;
#pragma unroll
    for (int c = 0; c < CHUNKS; ++c) {
        scale[c] = __expf(pb[c * PSTRIDE + NH] - M);
        L += pb[c * PSTRIDE + NH + 1] * scale[c];
    }
    const float invL = 1.0f / L;

    float* ob = out + (size_t)b * 2 * NH;
    for (int h = tid; h < NH; h += NTHREADS) {
        float acc = 0.f;
#pragma unroll
        for (int c = 0; c < CHUNKS; ++c)
            acc += pb[c * PSTRIDE + h] * scale[c];
        ob[h]      = acc * invL;                    // context (f32)
        ob[NH + h] = dec[b * NH + h];               // dec passthrough (f32)
    }

    float* wb = out + (size_t)NB * 2 * NH + (size_t)b * NS;
    const float* sc = scores + (size_t)b * NS;
    for (int s = tid; s < NS; s += NTHREADS)
        wb[s] = __expf(sc[s] - M) * invL;           // weights (f32)
}

extern "C" void kernel_launch(void* const* d_in, const int* in_sizes, int n_in,
                              void* d_out, int out_size, void* d_ws, size_t ws_size,
                              hipStream_t stream)
{
    // Disambiguate inputs by element count (dec = 65536, enc = 268435456).
    const float* enc;
    const float* dec;
    if (in_sizes[0] == NB * NH) {
        dec = (const float*)d_in[0];
        enc = (const float*)d_in[1];
    } else {
        enc = (const float*)d_in[0];
        dec = (const float*)d_in[1];
    }
    float* out = (float*)d_out;

    // ws: scores f32[64*4096] (1 MiB) + partials f32[64*16*(1024+2)] (~4.2 MiB)
    float* scores   = (float*)d_ws;
    float* partials = scores + (size_t)NB * NS;

    dotattn_pass_a<<<NB * CHUNKS, NTHREADS, 0, stream>>>(enc, dec, scores, partials);
    dotattn_finalize<<<NB, NTHREADS, 0, stream>>>(dec, scores, partials, out);
}

// Round 5
// 202.381 us; speedup vs baseline: 1.0065x; 1.0065x over previous
//
#include <hip/hip_runtime.h>
#include <hip/hip_bf16.h>

// DotAttention: B=64, S=4096, H=1024, f32 inputs, f32 outputs.
// out layout (flat f32): [B, 2H] concat(context, dec)  then  [B, S] weights.
//
// Split-S single-pass-over-enc with online softmax:
//   pass_a  : per (b, chunk) -> partial (ctx[H], m, l) + raw scores  (1024 blocks)
//             2-row unrolled: 8 VMEM in flight/lane, interleaved butterflies.
//   finalize: merge 16 partials per batch, emit f32 outputs          (256 blocks)

#define NB 64
#define NS 4096
#define NH 1024
#define CHUNKS 16
#define ROWS (NS / CHUNKS)            // 256 rows per block
#define NTHREADS 256
#define NWAVES 4
#define PAIRS (ROWS / (NWAVES * 2))   // 32 row-pairs per wave
#define PSTRIDE (NH + 2)              // ctx[NH], m, l

__global__ __launch_bounds__(NTHREADS)
void dotattn_pass_a(const float* __restrict__ enc, const float* __restrict__ dec,
                    float* __restrict__ scores, float* __restrict__ partials)
{
    const int blk   = blockIdx.x;
    const int b     = blk >> 4;    // / CHUNKS
    const int chunk = blk & 15;    // % CHUNKS
    const int tid   = threadIdx.x;
    const int lane  = tid & 63;
    const int wave  = tid >> 6;

    // Lane owns h-slice {lane*4 + k*256 + j : k,j in 0..3} (16 of 1024).
    const float* decb = dec + b * NH;
    float4 dreg[4];
#pragma unroll
    for (int k = 0; k < 4; ++k)
        dreg[k] = *reinterpret_cast<const float4*>(decb + lane * 4 + k * 256);

    float4 ctx[4];
#pragma unroll
    for (int k = 0; k < 4; ++k) ctx[k] = make_float4(0.f, 0.f, 0.f, 0.f);
    float m = -3.0e38f, l = 0.f;

    const int s0 = chunk * ROWS;
    const float* encb = enc + (size_t)b * NS * NH;

    // Wave processes row pairs: s(i) = s0 + 8*i + 2*wave, s(i)+1.
    float4 en0[4], en1[4];
    {
        const size_t base = (size_t)(s0 + 2 * wave) * NH + lane * 4;
#pragma unroll
        for (int k = 0; k < 4; ++k) {
            en0[k] = *reinterpret_cast<const float4*>(encb + base + k * 256);
            en1[k] = *reinterpret_cast<const float4*>(encb + base + NH + k * 256);
        }
    }

    for (int i = 0; i < PAIRS; ++i) {
        const int s = s0 + 8 * i + 2 * wave;
        float4 e0[4], e1[4];
#pragma unroll
        for (int k = 0; k < 4; ++k) { e0[k] = en0[k]; e1[k] = en1[k]; }

        if (i + 1 < PAIRS) {                       // prefetch next pair
            const size_t nbase = (size_t)(s + 8) * NH + lane * 4;
#pragma unroll
            for (int k = 0; k < 4; ++k) {
                en0[k] = *reinterpret_cast<const float4*>(encb + nbase + k * 256);
                en1[k] = *reinterpret_cast<const float4*>(encb + nbase + NH + k * 256);
            }
        }

        float p0 = 0.f, p1 = 0.f;
#pragma unroll
        for (int k = 0; k < 4; ++k) {
            p0 += e0[k].x * dreg[k].x; p1 += e1[k].x * dreg[k].x;
            p0 += e0[k].y * dreg[k].y; p1 += e1[k].y * dreg[k].y;
            p0 += e0[k].z * dreg[k].z; p1 += e1[k].z * dreg[k].z;
            p0 += e0[k].w * dreg[k].w; p1 += e1[k].w * dreg[k].w;
        }
        // two independent butterflies, interleaved by the scheduler
#pragma unroll
        for (int off = 32; off >= 1; off >>= 1) {
            p0 += __shfl_xor(p0, off, 64);
            p1 += __shfl_xor(p1, off, 64);
        }

        if (lane == 0)
            *reinterpret_cast<float2*>(&scores[b * NS + s]) = make_float2(p0, p1);

        const float pm = fmaxf(p0, p1);
        if (pm > m) {                               // wave-uniform, rare
            const float sc = __expf(m - pm);
            l *= sc;
#pragma unroll
            for (int k = 0; k < 4; ++k) {
                ctx[k].x *= sc; ctx[k].y *= sc; ctx[k].z *= sc; ctx[k].w *= sc;
            }
            m = pm;
        }
        const float w0 = __expf(p0 - m);
        const float w1 = __expf(p1 - m);
        l += w0 + w1;
#pragma unroll
        for (int k = 0; k < 4; ++k) {               // reuse enc rows in-register
            ctx[k].x += w0 * e0[k].x + w1 * e1[k].x;
            ctx[k].y += w0 * e0[k].y + w1 * e1[k].y;
            ctx[k].z += w0 * e0[k].z + w1 * e1[k].z;
            ctx[k].w += w0 * e0[k].w + w1 * e1[k].w;
        }
    }

    // ---- combine 4 waves -> one partial per block ----
    __shared__ float sml[NWAVES][2];
    __shared__ float sctx[NWAVES][NH];             // 16 KiB

    if (lane == 0) { sml[wave][0] = m; sml[wave][1] = l; }
    __syncthreads();

    const float M = fmaxf(fmaxf(sml[0][0], sml[1][0]), fmaxf(sml[2][0], sml[3][0]));
    float L = 0.f;
#pragma unroll
    for (int wv = 0; wv < NWAVES; ++wv)
        L += sml[wv][1] * __expf(sml[wv][0] - M);

    const float msc = __expf(m - M);               // wave-uniform
#pragma unroll
    for (int k = 0; k < 4; ++k) {
        float4 v = make_float4(ctx[k].x * msc, ctx[k].y * msc,
                               ctx[k].z * msc, ctx[k].w * msc);
        *reinterpret_cast<float4*>(&sctx[wave][lane * 4 + k * 256]) = v;
    }
    __syncthreads();

    float* outp = partials + (size_t)(b * CHUNKS + chunk) * PSTRIDE;
    for (int h = tid; h < NH; h += NTHREADS)
        outp[h] = sctx[0][h] + sctx[1][h] + sctx[2][h] + sctx[3][h];
    if (tid == 0) { outp[NH] = M; outp[NH + 1] = L; }
}

__global__ __launch_bounds__(NTHREADS)
void dotattn_finalize(const float* __restrict__ dec, const float* __restrict__ scores,
                      const float* __restrict__ partials, float* __restrict__ out)
{
    const int b   = blockIdx.x >> 2;               // batch
    const int q   = blockIdx.x & 3;                // quarter
    const int tid = threadIdx.x;
    const float* pb = partials + (size_t)b * CHUNKS * PSTRIDE;

    float M = -3.0e38f;
#pragma unroll
    for (int c = 0; c < CHUNKS; ++c)
        M = fmaxf(M, pb[c * PSTRIDE + NH]);

    float scale[CHUNKS];
    float L = 0.f;
#pragma unroll
    for (int c = 0; c < CHUNKS; ++c) {
        scale[c] = __expf(pb[c * PSTRIDE + NH] - M);
        L += pb[c * PSTRIDE + NH + 1] * scale[c];
    }
    const float invL = 1.0f / L;

    // context + dec quarter: h in [q*256, q*256+256)
    {
        const int h = q * 256 + tid;
        float acc = 0.f;
#pragma unroll
        for (int c = 0; c < CHUNKS; ++c)
            acc += pb[c * PSTRIDE + h] * scale[c];
        float* ob = out + (size_t)b * 2 * NH;
        ob[h]      = acc * invL;                    // context
        ob[NH + h] = dec[b * NH + h];               // dec passthrough
    }

    // weights quarter: s in [q*1024, q*1024+1024)
    const float* sc = scores + (size_t)b * NS + q * 1024;
    float* wb = out + (size_t)NB * 2 * NH + (size_t)b * NS + q * 1024;
    for (int s = tid; s < 1024; s += NTHREADS)
        wb[s] = __expf(sc[s] - M) * invL;
}

extern "C" void kernel_launch(void* const* d_in, const int* in_sizes, int n_in,
                              void* d_out, int out_size, void* d_ws, size_t ws_size,
                              hipStream_t stream)
{
    // Disambiguate inputs by element count (dec = 65536, enc = 268435456).
    const float* enc;
    const float* dec;
    if (in_sizes[0] == NB * NH) {
        dec = (const float*)d_in[0];
        enc = (const float*)d_in[1];
    } else {
        enc = (const float*)d_in[0];
        dec = (const float*)d_in[1];
    }
    float* out = (float*)d_out;

    // ws: scores f32[64*4096] (1 MiB) + partials f32[64*16*(1024+2)] (~4.2 MiB)
    float* scores   = (float*)d_ws;
    float* partials = scores + (size_t)NB * NS;

    dotattn_pass_a<<<NB * CHUNKS, NTHREADS, 0, stream>>>(enc, dec, scores, partials);
    dotattn_finalize<<<NB * 4, NTHREADS, 0, stream>>>(dec, scores, partials, out);
}